// Round 18
// baseline (351.879 us; speedup 1.0000x reference)
//
#include <hip/hip_runtime.h>
#include <stdint.h>

typedef __bf16 bf16x8 __attribute__((ext_vector_type(8)));
typedef float f32x4 __attribute__((ext_vector_type(4)));

__device__ __forceinline__ unsigned short f2bf(float f) {
  unsigned int t = __builtin_bit_cast(unsigned int, f);
  t += 0x7FFFu + ((t >> 16) & 1u);
  return (unsigned short)(t >> 16);
}
__device__ __forceinline__ void gll16(const void* g, void* l) {
  __builtin_amdgcn_global_load_lds((const __attribute__((address_space(1))) void*)g,
                                   (__attribute__((address_space(3))) void*)l, 16, 0, 0);
}

// exact-GELU via Abramowitz-Stegun 7.1.26 rational erf approx (|eps|<=1.5e-7)
__device__ __forceinline__ float gelu_f(float x) {
  float u = x * 0.70710678118f;
  float ax = fabsf(u);
  float t = 1.0f / (1.0f + 0.3275911f * ax);
  float p = 1.061405429f;
  p = p * t - 1.453152027f;
  p = p * t + 1.421413741f;
  p = p * t - 0.284496736f;
  p = p * t + 0.254829592f;
  p = p * t;
  float erfv = 1.0f - p * __expf(-ax * ax);
  erfv = (u < 0.f) ? -erfv : erfv;
  return 0.5f * x * (1.0f + erfv);
}

// window-order row -> natural spatial row (cyclic shift map)
__device__ __forceinline__ int shiftmap_row(int r) {
  int win = r >> 8, n = r & 255;
  int wd = win >> 6, wh = (win >> 3) & 7, ww = win & 7;
  int ld = n >> 6, lh = (n >> 3) & 7, lw = n & 7;
  int d  = ((wd << 2) + ld + 2) & 7;
  int hh = ((wh << 3) + lh + 4) & 63;
  int wg = ((ww << 3) + lw + 4) & 63;
  return (d << 12) + (hh << 6) + wg;
}

// ---------------- fp32 -> bf16 weight conversion ----------------
__global__ __launch_bounds__(256) void cvt_kernel(const float* __restrict__ in,
                                                  unsigned short* __restrict__ outp) {
  int i = (blockIdx.x * 256 + threadIdx.x) * 4;
  float4 v = *(const float4*)(in + i);
  uint2 o;
  o.x = (unsigned int)f2bf(v.x) | ((unsigned int)f2bf(v.y) << 16);
  o.y = (unsigned int)f2bf(v.z) | ((unsigned int)f2bf(v.w) << 16);
  *(uint2*)(outp + i) = o;
}

// ---------------- LayerNorm: fp32 in -> bf16 out (one wave per token) ----------------
template <bool REMAP>
__global__ __launch_bounds__(256) void ln_kernel(const float* __restrict__ in,
                                                 const float* __restrict__ w,
                                                 const float* __restrict__ b,
                                                 unsigned short* __restrict__ outp,
                                                 int row0) {
  int rl = (blockIdx.x << 2) + (threadIdx.x >> 6);
  int lane = threadIdx.x & 63;
  int g = row0 + rl;
  size_t src = REMAP ? (size_t)shiftmap_row(g) : (size_t)g;
  const float2* px = (const float2*)(in + src * 384);
  float2 p0 = px[lane * 3 + 0], p1 = px[lane * 3 + 1], p2 = px[lane * 3 + 2];
  float v[6] = {p0.x, p0.y, p1.x, p1.y, p2.x, p2.y};
  float sm = 0.f, ss = 0.f;
#pragma unroll
  for (int j = 0; j < 6; ++j) { sm += v[j]; ss += v[j] * v[j]; }
#pragma unroll
  for (int m = 1; m < 64; m <<= 1) { sm += __shfl_xor(sm, m); ss += __shfl_xor(ss, m); }
  float mean = sm * (1.0f / 384.0f);
  float var = ss * (1.0f / 384.0f) - mean * mean;
  float rstd = rsqrtf(var + 1e-5f);
  const float2* pw = (const float2*)w;
  const float2* pb = (const float2*)b;
  unsigned int* po = (unsigned int*)(outp + (size_t)rl * 384);
#pragma unroll
  for (int j = 0; j < 3; ++j) {
    float2 uw = pw[lane * 3 + j], ub = pb[lane * 3 + j];
    float y0 = (v[2 * j] - mean) * rstd * uw.x + ub.x;
    float y1 = (v[2 * j + 1] - mean) * rstd * uw.y + ub.y;
    po[lane * 3 + j] = (unsigned int)f2bf(y0) | ((unsigned int)f2bf(y1) << 16);
  }
}

// ---------------- relative-position bias gather: biasTab[h][i][j] fp32 ----------------
__global__ __launch_bounds__(256) void bias_gather(const float* __restrict__ rpb,
                                                   float* __restrict__ biasTab) {
  int j = threadIdx.x, blk = blockIdx.x;
  int i = blk & 255, h = blk >> 8;
  int id = i >> 6, ih = (i >> 3) & 7, iw = i & 7;
  int jd = j >> 6, jh = (j >> 3) & 7, jw = j & 7;
  int idx = (id - jd + 3) * 225 + (ih - jh + 7) * 15 + (iw - jw + 7);
  biasTab[((size_t)h << 16) + (i << 8) + j] = rpb[idx * 12 + h];
}

// ---------------- NT GEMM v8: counted-vmcnt 3-buffer pipeline + line-coalesced stores ----------------
// (verified R11/R12) EPI 0: bf16 store  EPI 1: proj->fp32 scatter+residual
// EPI 2: GELU->bf16  EPI 3: residual add->fp32
template <int EPI, int TM, int BK, int KDIM>
__global__ __launch_bounds__(256) void gemm_nt(const unsigned short* __restrict__ A,
                                               const unsigned short* __restrict__ W,
                                               const float* __restrict__ bias,
                                               void* __restrict__ Cv,
                                               const float* __restrict__ res,
                                               int M, int N, int row0) {
  constexpr int MW = TM / 32;          // m-frags per wave
  constexpr int ROWB = BK * 2;         // bytes per LDS row
  constexpr int RPG = 128 / ROWB;      // rows per 128B bank-cycle
  constexpr int SLM = ROWB / 16 - 1;   // swizzle slot mask
  constexpr int KS = BK / 32;          // K-slices per step
  constexpr int ABYTES = TM * ROWB;
  constexpr int BBYTES = 128 * ROWB;
  constexpr int BUFB = ABYTES + BBYTES;
  constexpr int NA = ABYTES / 4096;    // gll16 issues per thread for A
  constexpr int NB = BBYTES / 4096;
  constexpr int G = NA + NB;           // vmcnt per stage (per wave)
  constexpr int NSTEPS = KDIM / BK;
  constexpr int MAIN = 3 * BUFB;
  constexpr int EPB = (EPI == 0 || EPI == 2) ? TM * 256 : 0;
  constexpr int LDSZ = MAIN > EPB ? MAIN : EPB;
  __shared__ __attribute__((aligned(16))) char lds[LDSZ];
  int ntiles = N >> 7;
  int nwg = (M / TM) * ntiles;
  int bid = blockIdx.x;
  {  // bijective XCD-aware swizzle (m204)
    int q = nwg >> 3, r = nwg & 7, xc = bid & 7, o = bid >> 3;
    bid = (xc < r ? xc * (q + 1) : r * (q + 1) + (xc - r) * q) + o;
  }
  int mt = bid / ntiles, nt = bid % ntiles;
  int m0 = mt * TM, n0 = nt << 7;
  int tid = threadIdx.x, lane = tid & 63, wave = tid >> 6;
  int wr = wave >> 1, wc = wave & 1;
  int rlo = lane & 15, khi = lane >> 4;
  f32x4 acc[MW][4] = {};

  const unsigned short* pa[NA];
  const unsigned short* pb[NB];
  int ldst = (wave << 10);
#pragma unroll
  for (int i = 0; i < NA; ++i) {
    int lb = (i << 12) + ldst + (lane << 4);
    int r = lb / ROWB;
    int cb = (lb % ROWB) ^ (((r / RPG) & SLM) << 4);
    pa[i] = A + (size_t)(m0 + r) * KDIM + (cb >> 1);
  }
#pragma unroll
  for (int i = 0; i < NB; ++i) {
    int lb = (i << 12) + ldst + (lane << 4);
    int r = lb / ROWB;
    int cb = (lb % ROWB) ^ (((r / RPG) & SLM) << 4);
    pb[i] = W + (size_t)(n0 + r) * KDIM + (cb >> 1);
  }
  int aoff[MW][KS], boff[4][KS];
#pragma unroll
  for (int m = 0; m < MW; ++m) {
    int rw = wr * (TM / 2) + (m << 4) + rlo;
    int swz = ((rw / RPG) & SLM) << 4;
#pragma unroll
    for (int kk = 0; kk < KS; ++kk)
      aoff[m][kk] = (rw * ROWB + (kk << 6) + (khi << 4)) ^ swz;
  }
#pragma unroll
  for (int n = 0; n < 4; ++n) {
    int rw = (wc << 6) + (n << 4) + rlo;
    int swz = ((rw / RPG) & SLM) << 4;
#pragma unroll
    for (int kk = 0; kk < KS; ++kk)
      boff[n][kk] = ABYTES + ((rw * ROWB + (kk << 6) + (khi << 4)) ^ swz);
  }

  auto stage = [&](int slot, int t) {
    const int bo = slot * BUFB;
#pragma unroll
    for (int i = 0; i < NA; ++i) gll16(pa[i] + t * BK, lds + bo + (i << 12) + ldst);
#pragma unroll
    for (int i = 0; i < NB; ++i) gll16(pb[i] + t * BK, lds + bo + ABYTES + (i << 12) + ldst);
  };

  stage(0, 0);
  __builtin_amdgcn_sched_barrier(0);
  if (NSTEPS > 1) stage(1, 1);
  __builtin_amdgcn_sched_barrier(0);
  asm volatile("s_waitcnt vmcnt(%0)" ::"n"(NSTEPS > 1 ? G : 0) : "memory");
  __builtin_amdgcn_s_barrier();
  __builtin_amdgcn_sched_barrier(0);

#pragma unroll
  for (int t = 0; t < NSTEPS; ++t) {
    if (t + 2 < NSTEPS) stage((t + 2) % 3, t + 2);
    __builtin_amdgcn_sched_barrier(0);
    const int bo = (t % 3) * BUFB;
#pragma unroll
    for (int kkk = 0; kkk < KS; ++kkk) {
      bf16x8 af[MW], bfr[4];
#pragma unroll
      for (int m = 0; m < MW; ++m)
        af[m] = __builtin_bit_cast(bf16x8, *(const uint4*)(lds + bo + aoff[m][kkk]));
#pragma unroll
      for (int n = 0; n < 4; ++n)
        bfr[n] = __builtin_bit_cast(bf16x8, *(const uint4*)(lds + bo + boff[n][kkk]));
#pragma unroll
      for (int m = 0; m < MW; ++m)
#pragma unroll
        for (int n = 0; n < 4; ++n)
          acc[m][n] = __builtin_amdgcn_mfma_f32_16x16x32_bf16(af[m], bfr[n], acc[m][n], 0, 0, 0);
    }
    if (t + 1 < NSTEPS) {
      __builtin_amdgcn_sched_barrier(0);
      if (t + 2 < NSTEPS) {
        asm volatile("s_waitcnt vmcnt(%0)" ::"n"(G) : "memory");
      } else {
        asm volatile("s_waitcnt vmcnt(0)" ::: "memory");
      }
      __builtin_amdgcn_s_barrier();
      __builtin_amdgcn_sched_barrier(0);
    }
  }

  if constexpr (EPI == 0 || EPI == 2) {
    __syncthreads();
    unsigned short* Cb = (unsigned short*)Cv;
#pragma unroll
    for (int m = 0; m < MW; ++m) {
#pragma unroll
      for (int r = 0; r < 4; ++r) {
        int rowl = wr * (TM / 2) + (m << 4) + (khi << 2) + r;
#pragma unroll
        for (int n = 0; n < 4; ++n) {
          int coll = (wc << 6) + (n << 4) + rlo;
          float v = acc[m][n][r] + bias[n0 + coll];
          if (EPI == 2) v = gelu_f(v);
          int off = ((rowl << 8) + (coll << 1)) ^ ((rowl & 7) << 4);
          *(unsigned short*)(lds + off) = f2bf(v);
        }
      }
    }
    __syncthreads();
    int slot = tid & 15;
#pragma unroll
    for (int i = 0; i < TM / 16; ++i) {
      int row = (i << 4) + (tid >> 4);
      int off = ((row << 8) + (slot << 4)) ^ ((row & 7) << 4);
      *(uint4*)(Cb + (size_t)(m0 + row) * N + n0 + (slot << 3)) = *(const uint4*)(lds + off);
    }
  } else {
    float* Cf = (float*)Cv;
#pragma unroll
    for (int m = 0; m < MW; ++m) {
#pragma unroll
      for (int r = 0; r < 4; ++r) {
        int row = m0 + wr * (TM / 2) + (m << 4) + (khi << 2) + r;
        size_t orow = (size_t)row;
        if (EPI == 1) orow = (size_t)shiftmap_row(row0 + row);
#pragma unroll
        for (int n = 0; n < 4; ++n) {
          int col = n0 + (wc << 6) + (n << 4) + rlo;
          float v = acc[m][n][r] + bias[col];
          if (EPI == 1) {
            v += res[orow * 384 + col];
            Cf[orow * 384 + col] = v;
          } else {
            v += res[(size_t)row * 384 + col];
            Cf[(size_t)row * 384 + col] = v;
          }
        }
      }
    }
  }
}

// ---------------- windowed attention (R12 structure + group-XCD swizzle, verified R17) ----------------
__global__ __launch_bounds__(256) void attn_kernel(const unsigned short* __restrict__ qkv,
                                                   const float* __restrict__ biasTab,
                                                   unsigned short* __restrict__ outp,
                                                   int win0) {
  __shared__ __attribute__((aligned(16))) unsigned short Vt[32][264];    // V^T, padded
  __shared__ __attribute__((aligned(16))) unsigned short P[4][16][264];  // per-wave P, padded
  __shared__ unsigned char lbl[256];
  int i = blockIdx.x;
  int qt = (i >> 3) & 3;                 // group-XCD swizzle (bijective: groups % 8 == 0)
  int grp = (i & 7) + ((i >> 5) << 3);
  int h = grp % 12;
  int winl = grp / 12;
  int wing = win0 + winl;
  size_t winbase = (size_t)winl << 8;
  int tid = threadIdx.x, lane = tid & 63, wave = tid >> 6;
  int rlo = lane & 15, khi = lane >> 4;

  {  // stage V transposed + region labels
    int n = tid;
    const uint4* vp = (const uint4*)(qkv + (winbase + n) * 1152 + 768 + h * 32);
    uint4 vv[4] = {vp[0], vp[1], vp[2], vp[3]};
    const unsigned short* vs = (const unsigned short*)vv;
#pragma unroll
    for (int d = 0; d < 32; ++d) Vt[d][n] = vs[d];
    int ld = n >> 6, lh = (n >> 3) & 7, lw = n & 7;
    int wd = wing >> 6, wh = (wing >> 3) & 7, ww = wing & 7;
    int dd = (wd << 2) + ld, hh = (wh << 3) + lh, wg = (ww << 3) + lw;
    int rd = (dd < 4) ? 0 : ((dd < 6) ? 1 : 2);
    int rh = (hh < 56) ? 0 : ((hh < 60) ? 1 : 2);
    int rw = (wg < 56) ? 0 : ((wg < 60) ? 1 : 2);
    lbl[n] = (unsigned char)(rd * 9 + rh * 3 + rw);
  }
  __syncthreads();

  int qrowbase = (qt << 6) + (wave << 4);
  bf16x8 qf = __builtin_bit_cast(bf16x8,
      *(const uint4*)(qkv + (winbase + qrowbase + rlo) * 1152 + h * 32 + (khi << 3)));

  f32x4 s[16];
#pragma unroll
  for (int jt = 0; jt < 16; ++jt) {
    bf16x8 kf = __builtin_bit_cast(bf16x8,
        *(const uint4*)(qkv + (winbase + (jt << 4) + rlo) * 1152 + 384 + h * 32 + (khi << 3)));
    f32x4 z = {0.f, 0.f, 0.f, 0.f};
    s[jt] = __builtin_amdgcn_mfma_f32_16x16x32_bf16(qf, kf, z, 0, 0, 0);
  }

  const float scale = 0.17677669529663687f;  // 1/sqrt(32)
  unsigned char li[4];
#pragma unroll
  for (int r = 0; r < 4; ++r) li[r] = lbl[qrowbase + (khi << 2) + r];

  float mx[4] = {-1e30f, -1e30f, -1e30f, -1e30f};
#pragma unroll
  for (int jt = 0; jt < 16; ++jt) {
    unsigned char lj = lbl[(jt << 4) + rlo];
#pragma unroll
    for (int r = 0; r < 4; ++r) {
      int qi = qrowbase + (khi << 2) + r;
      float bv = biasTab[((size_t)h << 16) + ((size_t)qi << 8) + (jt << 4) + rlo];
      float val = s[jt][r] * scale + bv + ((li[r] == lj) ? 0.f : -100.f);
      s[jt][r] = val;
      mx[r] = fmaxf(mx[r], val);
    }
  }
#pragma unroll
  for (int r = 0; r < 4; ++r)
#pragma unroll
    for (int m = 1; m < 16; m <<= 1) mx[r] = fmaxf(mx[r], __shfl_xor(mx[r], m));
  float sum[4] = {0.f, 0.f, 0.f, 0.f};
#pragma unroll
  for (int jt = 0; jt < 16; ++jt)
#pragma unroll
    for (int r = 0; r < 4; ++r) {
      float p = __expf(s[jt][r] - mx[r]);
      s[jt][r] = p;
      sum[r] += p;
    }
#pragma unroll
  for (int r = 0; r < 4; ++r) {
#pragma unroll
    for (int m = 1; m < 16; m <<= 1) sum[r] += __shfl_xor(sum[r], m);
    sum[r] = 1.0f / sum[r];
  }
#pragma unroll
  for (int jt = 0; jt < 16; ++jt)
#pragma unroll
    for (int r = 0; r < 4; ++r)
      P[wave][(khi << 2) + r][(jt << 4) + rlo] = f2bf(s[jt][r] * sum[r]);

  f32x4 o0 = {0.f, 0.f, 0.f, 0.f}, o1 = {0.f, 0.f, 0.f, 0.f};
#pragma unroll
  for (int kt = 0; kt < 8; ++kt) {
    bf16x8 pf = __builtin_bit_cast(bf16x8, *(const uint4*)&P[wave][rlo][(kt << 5) + (khi << 3)]);
    bf16x8 v0 = __builtin_bit_cast(bf16x8, *(const uint4*)&Vt[rlo][(kt << 5) + (khi << 3)]);
    bf16x8 v1 = __builtin_bit_cast(bf16x8, *(const uint4*)&Vt[16 + rlo][(kt << 5) + (khi << 3)]);
    o0 = __builtin_amdgcn_mfma_f32_16x16x32_bf16(pf, v0, o0, 0, 0, 0);
    o1 = __builtin_amdgcn_mfma_f32_16x16x32_bf16(pf, v1, o1, 0, 0, 0);
  }
  size_t obase = winbase + qrowbase + (khi << 2);
#pragma unroll
  for (int r = 0; r < 4; ++r) {
    size_t rowoff = (obase + r) * 384 + h * 32;
    outp[rowoff + rlo] = f2bf(o0[r]);
    outp[rowoff + 16 + rlo] = f2bf(o1[r]);
  }
}

extern "C" void kernel_launch(void* const* d_in, const int* in_sizes, int n_in,
                              void* d_out, int out_size, void* d_ws, size_t ws_size,
                              hipStream_t stream) {
  const float* x     = (const float*)d_in[0];
  const float* n1w   = (const float*)d_in[1];
  const float* n1b   = (const float*)d_in[2];
  const float* qkvw  = (const float*)d_in[3];
  const float* qkvb  = (const float*)d_in[4];
  const float* rpb   = (const float*)d_in[5];
  const float* projw = (const float*)d_in[6];
  const float* projb = (const float*)d_in[7];
  const float* n2w   = (const float*)d_in[8];
  const float* n2b   = (const float*)d_in[9];
  const float* fc1w  = (const float*)d_in[10];
  const float* fc1b  = (const float*)d_in[11];
  const float* fc2w  = (const float*)d_in[12];
  const float* fc2b  = (const float*)d_in[13];
  float* out = (float*)d_out;
  char* ws = (char*)d_ws;

  // fixed prefix: bf16 weights (3.54 MB) + biasTab (3.15 MB)
  unsigned short* qkvw_b  = (unsigned short*)(ws);
  unsigned short* projw_b = (unsigned short*)(ws + 884736);
  unsigned short* fc1w_b  = (unsigned short*)(ws + 1179648);
  unsigned short* fc2w_b  = (unsigned short*)(ws + 2359296);
  float*          biasTab = (float*)(ws + 3538944);
  char*           cbase   = ws + 6684672;

  // adaptive chunk size (ws_size is fixed per harness -> deterministic)
  int CH = 8192;
  if (ws_size >= 6684672UL + 32768UL * 3840UL) CH = 32768;
  else if (ws_size >= 6684672UL + 16384UL * 3840UL) CH = 16384;
  int nch = 32768 / CH;

  unsigned short* hwin_c  = (unsigned short*)(cbase);
  unsigned short* qkv_c   = (unsigned short*)(cbase + (size_t)CH * 768);
  unsigned short* attno_c = (unsigned short*)(cbase + (size_t)CH * 3072);
  unsigned short* h2_c = (unsigned short*)(cbase);
  unsigned short* a1_c = (unsigned short*)(cbase + (size_t)CH * 768);

  cvt_kernel<<<432, 256, 0, stream>>>(qkvw, qkvw_b);   // 1152*384
  cvt_kernel<<<144, 256, 0, stream>>>(projw, projw_b); // 384*384
  cvt_kernel<<<576, 256, 0, stream>>>(fc1w, fc1w_b);   // 1536*384
  cvt_kernel<<<576, 256, 0, stream>>>(fc2w, fc2w_b);   // 384*1536
  bias_gather<<<3072, 256, 0, stream>>>(rpb, biasTab);

  for (int c = 0; c < nch; ++c) {
    int row0 = c * CH, win0 = row0 >> 8;
    ln_kernel<true><<<CH / 4, 256, 0, stream>>>(x, n1w, n1b, hwin_c, row0);
    gemm_nt<0, 128, 32, 384><<<(CH / 128) * 9, 256, 0, stream>>>(hwin_c, qkvw_b, qkvb, qkv_c,
                                                                 nullptr, CH, 1152, row0);
    attn_kernel<<<(CH / 256) * 48, 256, 0, stream>>>(qkv_c, biasTab, attno_c, win0);
    gemm_nt<1, 64, 32, 384><<<(CH / 64) * 3, 256, 0, stream>>>(attno_c, projw_b, projb, out, x,
                                                               CH, 384, row0);
  }
  for (int c = 0; c < nch; ++c) {
    int row0 = c * CH;
    ln_kernel<false><<<CH / 4, 256, 0, stream>>>(out, n2w, n2b, h2_c, row0);
    gemm_nt<2, 64, 32, 384><<<(CH / 64) * 12, 256, 0, stream>>>(h2_c, fc1w_b, fc1b, a1_c,
                                                                nullptr, CH, 1536, row0);
    gemm_nt<3, 64, 32, 1536><<<(CH / 64) * 3, 256, 0, stream>>>(a1_c, fc2w_b, fc2b,
                                                                out + (size_t)row0 * 384,
                                                                out + (size_t)row0 * 384,
                                                                CH, 384, row0);
  }
}

// Round 19
// 333.190 us; speedup vs baseline: 1.0561x; 1.0561x over previous
//
#include <hip/hip_runtime.h>
#include <stdint.h>

typedef __bf16 bf16x8 __attribute__((ext_vector_type(8)));
typedef float f32x4 __attribute__((ext_vector_type(4)));

__device__ __forceinline__ unsigned short f2bf(float f) {
  unsigned int t = __builtin_bit_cast(unsigned int, f);
  t += 0x7FFFu + ((t >> 16) & 1u);
  return (unsigned short)(t >> 16);
}
__device__ __forceinline__ void gll16(const void* g, void* l) {
  __builtin_amdgcn_global_load_lds((const __attribute__((address_space(1))) void*)g,
                                   (__attribute__((address_space(3))) void*)l, 16, 0, 0);
}

// exact-GELU via Abramowitz-Stegun 7.1.26 rational erf approx (|eps|<=1.5e-7)
__device__ __forceinline__ float gelu_f(float x) {
  float u = x * 0.70710678118f;
  float ax = fabsf(u);
  float t = 1.0f / (1.0f + 0.3275911f * ax);
  float p = 1.061405429f;
  p = p * t - 1.453152027f;
  p = p * t + 1.421413741f;
  p = p * t - 0.284496736f;
  p = p * t + 0.254829592f;
  p = p * t;
  float erfv = 1.0f - p * __expf(-ax * ax);
  erfv = (u < 0.f) ? -erfv : erfv;
  return 0.5f * x * (1.0f + erfv);
}

// window-order row -> natural spatial row (cyclic shift map)
__device__ __forceinline__ int shiftmap_row(int r) {
  int win = r >> 8, n = r & 255;
  int wd = win >> 6, wh = (win >> 3) & 7, ww = win & 7;
  int ld = n >> 6, lh = (n >> 3) & 7, lw = n & 7;
  int d  = ((wd << 2) + ld + 2) & 7;
  int hh = ((wh << 3) + lh + 4) & 63;
  int wg = ((ww << 3) + lw + 4) & 63;
  return (d << 12) + (hh << 6) + wg;
}

// ---------------- fp32 -> bf16 weight conversion ----------------
__global__ __launch_bounds__(256) void cvt_kernel(const float* __restrict__ in,
                                                  unsigned short* __restrict__ outp) {
  int i = (blockIdx.x * 256 + threadIdx.x) * 4;
  float4 v = *(const float4*)(in + i);
  uint2 o;
  o.x = (unsigned int)f2bf(v.x) | ((unsigned int)f2bf(v.y) << 16);
  o.y = (unsigned int)f2bf(v.z) | ((unsigned int)f2bf(v.w) << 16);
  *(uint2*)(outp + i) = o;
}

// ---------------- LayerNorm: fp32 in -> bf16 out (one wave per token) ----------------
template <bool REMAP>
__global__ __launch_bounds__(256) void ln_kernel(const float* __restrict__ in,
                                                 const float* __restrict__ w,
                                                 const float* __restrict__ b,
                                                 unsigned short* __restrict__ outp,
                                                 int row0) {
  int rl = (blockIdx.x << 2) + (threadIdx.x >> 6);
  int lane = threadIdx.x & 63;
  int g = row0 + rl;
  size_t src = REMAP ? (size_t)shiftmap_row(g) : (size_t)g;
  const float2* px = (const float2*)(in + src * 384);
  float2 p0 = px[lane * 3 + 0], p1 = px[lane * 3 + 1], p2 = px[lane * 3 + 2];
  float v[6] = {p0.x, p0.y, p1.x, p1.y, p2.x, p2.y};
  float sm = 0.f, ss = 0.f;
#pragma unroll
  for (int j = 0; j < 6; ++j) { sm += v[j]; ss += v[j] * v[j]; }
#pragma unroll
  for (int m = 1; m < 64; m <<= 1) { sm += __shfl_xor(sm, m); ss += __shfl_xor(ss, m); }
  float mean = sm * (1.0f / 384.0f);
  float var = ss * (1.0f / 384.0f) - mean * mean;
  float rstd = rsqrtf(var + 1e-5f);
  const float2* pw = (const float2*)w;
  const float2* pb = (const float2*)b;
  unsigned int* po = (unsigned int*)(outp + (size_t)rl * 384);
#pragma unroll
  for (int j = 0; j < 3; ++j) {
    float2 uw = pw[lane * 3 + j], ub = pb[lane * 3 + j];
    float y0 = (v[2 * j] - mean) * rstd * uw.x + ub.x;
    float y1 = (v[2 * j + 1] - mean) * rstd * uw.y + ub.y;
    po[lane * 3 + j] = (unsigned int)f2bf(y0) | ((unsigned int)f2bf(y1) << 16);
  }
}

// ---------------- relative-position bias gather: biasTab[h][i][j] fp32 ----------------
__global__ __launch_bounds__(256) void bias_gather(const float* __restrict__ rpb,
                                                   float* __restrict__ biasTab) {
  int j = threadIdx.x, blk = blockIdx.x;
  int i = blk & 255, h = blk >> 8;
  int id = i >> 6, ih = (i >> 3) & 7, iw = i & 7;
  int jd = j >> 6, jh = (j >> 3) & 7, jw = j & 7;
  int idx = (id - jd + 3) * 225 + (ih - jh + 7) * 15 + (iw - jw + 7);
  biasTab[((size_t)h << 16) + (i << 8) + j] = rpb[idx * 12 + h];
}

// ---------------- NT GEMM v8: counted-vmcnt 3-buffer pipeline + line-coalesced stores ----------------
// (verified R11/R12) EPI 0: bf16 store  EPI 1: proj->fp32 scatter+residual
// EPI 2: GELU->bf16  EPI 3: residual add->fp32
template <int EPI, int TM, int BK, int KDIM>
__global__ __launch_bounds__(256) void gemm_nt(const unsigned short* __restrict__ A,
                                               const unsigned short* __restrict__ W,
                                               const float* __restrict__ bias,
                                               void* __restrict__ Cv,
                                               const float* __restrict__ res,
                                               int M, int N, int row0) {
  constexpr int MW = TM / 32;          // m-frags per wave
  constexpr int ROWB = BK * 2;         // bytes per LDS row
  constexpr int RPG = 128 / ROWB;      // rows per 128B bank-cycle
  constexpr int SLM = ROWB / 16 - 1;   // swizzle slot mask
  constexpr int KS = BK / 32;          // K-slices per step
  constexpr int ABYTES = TM * ROWB;
  constexpr int BBYTES = 128 * ROWB;
  constexpr int BUFB = ABYTES + BBYTES;
  constexpr int NA = ABYTES / 4096;    // gll16 issues per thread for A
  constexpr int NB = BBYTES / 4096;
  constexpr int G = NA + NB;           // vmcnt per stage (per wave)
  constexpr int NSTEPS = KDIM / BK;
  constexpr int MAIN = 3 * BUFB;
  constexpr int EPB = (EPI == 0 || EPI == 2) ? TM * 256 : 0;
  constexpr int LDSZ = MAIN > EPB ? MAIN : EPB;
  __shared__ __attribute__((aligned(16))) char lds[LDSZ];
  int ntiles = N >> 7;
  int nwg = (M / TM) * ntiles;
  int bid = blockIdx.x;
  {  // bijective XCD-aware swizzle (m204)
    int q = nwg >> 3, r = nwg & 7, xc = bid & 7, o = bid >> 3;
    bid = (xc < r ? xc * (q + 1) : r * (q + 1) + (xc - r) * q) + o;
  }
  int mt = bid / ntiles, nt = bid % ntiles;
  int m0 = mt * TM, n0 = nt << 7;
  int tid = threadIdx.x, lane = tid & 63, wave = tid >> 6;
  int wr = wave >> 1, wc = wave & 1;
  int rlo = lane & 15, khi = lane >> 4;
  f32x4 acc[MW][4] = {};

  const unsigned short* pa[NA];
  const unsigned short* pb[NB];
  int ldst = (wave << 10);
#pragma unroll
  for (int i = 0; i < NA; ++i) {
    int lb = (i << 12) + ldst + (lane << 4);
    int r = lb / ROWB;
    int cb = (lb % ROWB) ^ (((r / RPG) & SLM) << 4);
    pa[i] = A + (size_t)(m0 + r) * KDIM + (cb >> 1);
  }
#pragma unroll
  for (int i = 0; i < NB; ++i) {
    int lb = (i << 12) + ldst + (lane << 4);
    int r = lb / ROWB;
    int cb = (lb % ROWB) ^ (((r / RPG) & SLM) << 4);
    pb[i] = W + (size_t)(n0 + r) * KDIM + (cb >> 1);
  }
  int aoff[MW][KS], boff[4][KS];
#pragma unroll
  for (int m = 0; m < MW; ++m) {
    int rw = wr * (TM / 2) + (m << 4) + rlo;
    int swz = ((rw / RPG) & SLM) << 4;
#pragma unroll
    for (int kk = 0; kk < KS; ++kk)
      aoff[m][kk] = (rw * ROWB + (kk << 6) + (khi << 4)) ^ swz;
  }
#pragma unroll
  for (int n = 0; n < 4; ++n) {
    int rw = (wc << 6) + (n << 4) + rlo;
    int swz = ((rw / RPG) & SLM) << 4;
#pragma unroll
    for (int kk = 0; kk < KS; ++kk)
      boff[n][kk] = ABYTES + ((rw * ROWB + (kk << 6) + (khi << 4)) ^ swz);
  }

  auto stage = [&](int slot, int t) {
    const int bo = slot * BUFB;
#pragma unroll
    for (int i = 0; i < NA; ++i) gll16(pa[i] + t * BK, lds + bo + (i << 12) + ldst);
#pragma unroll
    for (int i = 0; i < NB; ++i) gll16(pb[i] + t * BK, lds + bo + ABYTES + (i << 12) + ldst);
  };

  stage(0, 0);
  __builtin_amdgcn_sched_barrier(0);
  if (NSTEPS > 1) stage(1, 1);
  __builtin_amdgcn_sched_barrier(0);
  asm volatile("s_waitcnt vmcnt(%0)" ::"n"(NSTEPS > 1 ? G : 0) : "memory");
  __builtin_amdgcn_s_barrier();
  __builtin_amdgcn_sched_barrier(0);

#pragma unroll
  for (int t = 0; t < NSTEPS; ++t) {
    if (t + 2 < NSTEPS) stage((t + 2) % 3, t + 2);
    __builtin_amdgcn_sched_barrier(0);
    const int bo = (t % 3) * BUFB;
#pragma unroll
    for (int kkk = 0; kkk < KS; ++kkk) {
      bf16x8 af[MW], bfr[4];
#pragma unroll
      for (int m = 0; m < MW; ++m)
        af[m] = __builtin_bit_cast(bf16x8, *(const uint4*)(lds + bo + aoff[m][kkk]));
#pragma unroll
      for (int n = 0; n < 4; ++n)
        bfr[n] = __builtin_bit_cast(bf16x8, *(const uint4*)(lds + bo + boff[n][kkk]));
#pragma unroll
      for (int m = 0; m < MW; ++m)
#pragma unroll
        for (int n = 0; n < 4; ++n)
          acc[m][n] = __builtin_amdgcn_mfma_f32_16x16x32_bf16(af[m], bfr[n], acc[m][n], 0, 0, 0);
    }
    if (t + 1 < NSTEPS) {
      __builtin_amdgcn_sched_barrier(0);
      if (t + 2 < NSTEPS) {
        asm volatile("s_waitcnt vmcnt(%0)" ::"n"(G) : "memory");
      } else {
        asm volatile("s_waitcnt vmcnt(0)" ::: "memory");
      }
      __builtin_amdgcn_s_barrier();
      __builtin_amdgcn_sched_barrier(0);
    }
  }

  if constexpr (EPI == 0 || EPI == 2) {
    __syncthreads();
    unsigned short* Cb = (unsigned short*)Cv;
#pragma unroll
    for (int m = 0; m < MW; ++m) {
#pragma unroll
      for (int r = 0; r < 4; ++r) {
        int rowl = wr * (TM / 2) + (m << 4) + (khi << 2) + r;
#pragma unroll
        for (int n = 0; n < 4; ++n) {
          int coll = (wc << 6) + (n << 4) + rlo;
          float v = acc[m][n][r] + bias[n0 + coll];
          if (EPI == 2) v = gelu_f(v);
          int off = ((rowl << 8) + (coll << 1)) ^ ((rowl & 7) << 4);
          *(unsigned short*)(lds + off) = f2bf(v);
        }
      }
    }
    __syncthreads();
    int slot = tid & 15;
#pragma unroll
    for (int i = 0; i < TM / 16; ++i) {
      int row = (i << 4) + (tid >> 4);
      int off = ((row << 8) + (slot << 4)) ^ ((row & 7) << 4);
      *(uint4*)(Cb + (size_t)(m0 + row) * N + n0 + (slot << 3)) = *(const uint4*)(lds + off);
    }
  } else {
    float* Cf = (float*)Cv;
#pragma unroll
    for (int m = 0; m < MW; ++m) {
#pragma unroll
      for (int r = 0; r < 4; ++r) {
        int row = m0 + wr * (TM / 2) + (m << 4) + (khi << 2) + r;
        size_t orow = (size_t)row;
        if (EPI == 1) orow = (size_t)shiftmap_row(row0 + row);
#pragma unroll
        for (int n = 0; n < 4; ++n) {
          int col = n0 + (wc << 6) + (n << 4) + rlo;
          float v = acc[m][n][r] + bias[col];
          if (EPI == 1) {
            v += res[orow * 384 + col];
            Cf[orow * 384 + col] = v;
          } else {
            v += res[(size_t)row * 384 + col];
            Cf[(size_t)row * 384 + col] = v;
          }
        }
      }
    }
  }
}

// ---------------- windowed attention v3: group-XCD swizzle + halved P LDS ----------------
// Block = (win, head, qtile). P buffer split into two k-halves processed sequentially --
// P is wave-private, so no barriers needed; LDS 51.2 -> 34.8 KB => 4 blocks/CU (was 3).
__global__ __launch_bounds__(256) void attn_kernel(const unsigned short* __restrict__ qkv,
                                                   const float* __restrict__ biasTab,
                                                   unsigned short* __restrict__ outp,
                                                   int win0) {
  __shared__ __attribute__((aligned(16))) unsigned short Vt[32][264];    // V^T, padded
  __shared__ __attribute__((aligned(16))) unsigned short P[4][16][136];  // per-wave P (k-half)
  __shared__ unsigned char lbl[256];
  int i = blockIdx.x;
  int qt = (i >> 3) & 3;                 // group-XCD swizzle (bijective: groups % 8 == 0)
  int grp = (i & 7) + ((i >> 5) << 3);
  int h = grp % 12;
  int winl = grp / 12;
  int wing = win0 + winl;
  size_t winbase = (size_t)winl << 8;
  int tid = threadIdx.x, lane = tid & 63, wave = tid >> 6;
  int rlo = lane & 15, khi = lane >> 4;

  {  // stage V transposed + region labels
    int n = tid;
    const uint4* vp = (const uint4*)(qkv + (winbase + n) * 1152 + 768 + h * 32);
    uint4 vv[4] = {vp[0], vp[1], vp[2], vp[3]};
    const unsigned short* vs = (const unsigned short*)vv;
#pragma unroll
    for (int d = 0; d < 32; ++d) Vt[d][n] = vs[d];
    int ld = n >> 6, lh = (n >> 3) & 7, lw = n & 7;
    int wd = wing >> 6, wh = (wing >> 3) & 7, ww = wing & 7;
    int dd = (wd << 2) + ld, hh = (wh << 3) + lh, wg = (ww << 3) + lw;
    int rd = (dd < 4) ? 0 : ((dd < 6) ? 1 : 2);
    int rh = (hh < 56) ? 0 : ((hh < 60) ? 1 : 2);
    int rw = (wg < 56) ? 0 : ((wg < 60) ? 1 : 2);
    lbl[n] = (unsigned char)(rd * 9 + rh * 3 + rw);
  }
  __syncthreads();

  int qrowbase = (qt << 6) + (wave << 4);
  bf16x8 qf = __builtin_bit_cast(bf16x8,
      *(const uint4*)(qkv + (winbase + qrowbase + rlo) * 1152 + h * 32 + (khi << 3)));

  f32x4 s[16];
#pragma unroll
  for (int jt = 0; jt < 16; ++jt) {
    bf16x8 kf = __builtin_bit_cast(bf16x8,
        *(const uint4*)(qkv + (winbase + (jt << 4) + rlo) * 1152 + 384 + h * 32 + (khi << 3)));
    f32x4 z = {0.f, 0.f, 0.f, 0.f};
    s[jt] = __builtin_amdgcn_mfma_f32_16x16x32_bf16(qf, kf, z, 0, 0, 0);
  }

  const float scale = 0.17677669529663687f;  // 1/sqrt(32)
  unsigned char li[4];
#pragma unroll
  for (int r = 0; r < 4; ++r) li[r] = lbl[qrowbase + (khi << 2) + r];

  float mx[4] = {-1e30f, -1e30f, -1e30f, -1e30f};
#pragma unroll
  for (int jt = 0; jt < 16; ++jt) {
    unsigned char lj = lbl[(jt << 4) + rlo];
#pragma unroll
    for (int r = 0; r < 4; ++r) {
      int qi = qrowbase + (khi << 2) + r;
      float bv = biasTab[((size_t)h << 16) + ((size_t)qi << 8) + (jt << 4) + rlo];
      float val = s[jt][r] * scale + bv + ((li[r] == lj) ? 0.f : -100.f);
      s[jt][r] = val;
      mx[r] = fmaxf(mx[r], val);
    }
  }
#pragma unroll
  for (int r = 0; r < 4; ++r)
#pragma unroll
    for (int m = 1; m < 16; m <<= 1) mx[r] = fmaxf(mx[r], __shfl_xor(mx[r], m));
  float sum[4] = {0.f, 0.f, 0.f, 0.f};
#pragma unroll
  for (int jt = 0; jt < 16; ++jt)
#pragma unroll
    for (int r = 0; r < 4; ++r) {
      float p = __expf(s[jt][r] - mx[r]);
      s[jt][r] = p;
      sum[r] += p;
    }
#pragma unroll
  for (int r = 0; r < 4; ++r) {
#pragma unroll
    for (int m = 1; m < 16; m <<= 1) sum[r] += __shfl_xor(sum[r], m);
    sum[r] = 1.0f / sum[r];
  }

  f32x4 o0 = {0.f, 0.f, 0.f, 0.f}, o1 = {0.f, 0.f, 0.f, 0.f};
#pragma unroll
  for (int half = 0; half < 2; ++half) {
    // write this k-half of P (wave-private; in-wave LDS ordering is compiler-tracked)
#pragma unroll
    for (int jt8 = 0; jt8 < 8; ++jt8) {
      int jt = (half << 3) + jt8;
#pragma unroll
      for (int r = 0; r < 4; ++r)
        P[wave][(khi << 2) + r][(jt8 << 4) + rlo] = f2bf(s[jt][r] * sum[r]);
    }
#pragma unroll
    for (int kt4 = 0; kt4 < 4; ++kt4) {
      int kt = (half << 2) + kt4;
      bf16x8 pf = __builtin_bit_cast(bf16x8, *(const uint4*)&P[wave][rlo][(kt4 << 5) + (khi << 3)]);
      bf16x8 v0 = __builtin_bit_cast(bf16x8, *(const uint4*)&Vt[rlo][(kt << 5) + (khi << 3)]);
      bf16x8 v1 = __builtin_bit_cast(bf16x8, *(const uint4*)&Vt[16 + rlo][(kt << 5) + (khi << 3)]);
      o0 = __builtin_amdgcn_mfma_f32_16x16x32_bf16(pf, v0, o0, 0, 0, 0);
      o1 = __builtin_amdgcn_mfma_f32_16x16x32_bf16(pf, v1, o1, 0, 0, 0);
    }
  }
  size_t obase = winbase + qrowbase + (khi << 2);
#pragma unroll
  for (int r = 0; r < 4; ++r) {
    size_t rowoff = (obase + r) * 384 + h * 32;
    outp[rowoff + rlo] = f2bf(o0[r]);
    outp[rowoff + 16 + rlo] = f2bf(o1[r]);
  }
}

extern "C" void kernel_launch(void* const* d_in, const int* in_sizes, int n_in,
                              void* d_out, int out_size, void* d_ws, size_t ws_size,
                              hipStream_t stream) {
  const float* x     = (const float*)d_in[0];
  const float* n1w   = (const float*)d_in[1];
  const float* n1b   = (const float*)d_in[2];
  const float* qkvw  = (const float*)d_in[3];
  const float* qkvb  = (const float*)d_in[4];
  const float* rpb   = (const float*)d_in[5];
  const float* projw = (const float*)d_in[6];
  const float* projb = (const float*)d_in[7];
  const float* n2w   = (const float*)d_in[8];
  const float* n2b   = (const float*)d_in[9];
  const float* fc1w  = (const float*)d_in[10];
  const float* fc1b  = (const float*)d_in[11];
  const float* fc2w  = (const float*)d_in[12];
  const float* fc2b  = (const float*)d_in[13];
  float* out = (float*)d_out;
  char* ws = (char*)d_ws;

  // fixed prefix: bf16 weights (3.54 MB) + biasTab (3.15 MB)
  unsigned short* qkvw_b  = (unsigned short*)(ws);
  unsigned short* projw_b = (unsigned short*)(ws + 884736);
  unsigned short* fc1w_b  = (unsigned short*)(ws + 1179648);
  unsigned short* fc2w_b  = (unsigned short*)(ws + 2359296);
  float*          biasTab = (float*)(ws + 3538944);
  char*           cbase   = ws + 6684672;

  // adaptive chunk size (ws_size is fixed per harness -> deterministic)
  int CH = 8192;
  if (ws_size >= 6684672UL + 32768UL * 3840UL) CH = 32768;
  else if (ws_size >= 6684672UL + 16384UL * 3840UL) CH = 16384;
  int nch = 32768 / CH;

  unsigned short* hwin_c  = (unsigned short*)(cbase);
  unsigned short* qkv_c   = (unsigned short*)(cbase + (size_t)CH * 768);
  unsigned short* attno_c = (unsigned short*)(cbase + (size_t)CH * 3072);
  unsigned short* h2_c = (unsigned short*)(cbase);
  unsigned short* a1_c = (unsigned short*)(cbase + (size_t)CH * 768);

  cvt_kernel<<<432, 256, 0, stream>>>(qkvw, qkvw_b);   // 1152*384
  cvt_kernel<<<144, 256, 0, stream>>>(projw, projw_b); // 384*384
  cvt_kernel<<<576, 256, 0, stream>>>(fc1w, fc1w_b);   // 1536*384
  cvt_kernel<<<576, 256, 0, stream>>>(fc2w, fc2w_b);   // 384*1536
  bias_gather<<<3072, 256, 0, stream>>>(rpb, biasTab);

  for (int c = 0; c < nch; ++c) {
    int row0 = c * CH, win0 = row0 >> 8;
    ln_kernel<true><<<CH / 4, 256, 0, stream>>>(x, n1w, n1b, hwin_c, row0);
    gemm_nt<0, 128, 32, 384><<<(CH / 128) * 9, 256, 0, stream>>>(hwin_c, qkvw_b, qkvb, qkv_c,
                                                                 nullptr, CH, 1152, row0);
    attn_kernel<<<(CH / 256) * 48, 256, 0, stream>>>(qkv_c, biasTab, attno_c, win0);
    gemm_nt<1, 64, 32, 384><<<(CH / 64) * 3, 256, 0, stream>>>(attno_c, projw_b, projb, out, x,
                                                               CH, 384, row0);
  }
  for (int c = 0; c < nch; ++c) {
    int row0 = c * CH;
    ln_kernel<false><<<CH / 4, 256, 0, stream>>>(out, n2w, n2b, h2_c, row0);
    gemm_nt<2, 128, 32, 384><<<(CH / 128) * 12, 256, 0, stream>>>(h2_c, fc1w_b, fc1b, a1_c,
                                                                  nullptr, CH, 1536, row0);
    gemm_nt<3, 128, 32, 1536><<<(CH / 128) * 3, 256, 0, stream>>>(a1_c, fc2w_b, fc2b,
                                                                  out + (size_t)row0 * 384,
                                                                  out + (size_t)row0 * 384,
                                                                  CH, 384, row0);
  }
}